// Round 2
// 4392.738 us; speedup vs baseline: 1.0641x; 1.0641x over previous
//
#include <hip/hip_runtime.h>

#define TT 11
#define NE 100000
#define NTX 100000
#define DD 128
#define EE 500000
#define FF 394
#define NBLK 391  // (NE+255)/256

__device__ __forceinline__ float leaky(float x) { return x >= 0.f ? x : 0.2f * x; }

// ============================================================
// GEMM family: C[M x 128] = A[M x K] @ B[K x 128]
// 128x128 block tile, 256 threads, 8x8 outputs/thread, k-chunk 32.
// As stored TRANSPOSED [32][132] so both operands load as ds_read_b128.
// thread (ty=tid>>4, tx=tid&15): rows 8ty..8ty+7, cols {4tx..4tx+3, 64+4tx..67+4tx}
// ============================================================

// acc1 = tx_x @ w1[0:FF] + b1
__global__ __launch_bounds__(256) void k_init_gemm(
    const float* __restrict__ A, const float* __restrict__ B,
    const float* __restrict__ bias, float* __restrict__ C) {
  __shared__ float As[32][132];
  __shared__ float Bs[32][128];
  int tid = threadIdx.x;
  int tx = tid & 15, ty = tid >> 4;
  int row0 = blockIdx.x * 128;
  int lkq = tid & 7, lr = tid >> 3;    // A staging
  int lc4 = tid & 31, lkb = tid >> 5;  // B staging
  float acc[8][8];
  #pragma unroll
  for (int i = 0; i < 8; ++i)
    #pragma unroll
    for (int j = 0; j < 8; ++j) acc[i][j] = 0.f;

  for (int k0 = 0; k0 < FF; k0 += 32) {
    #pragma unroll
    for (int p = 0; p < 4; ++p) {
      int r = lr + 32 * p;
      int rg = row0 + r;
      int kg = k0 + 4 * lkq;
      float4 v = make_float4(0.f, 0.f, 0.f, 0.f);
      if (rg < NTX) {
        const float* ap = A + (size_t)rg * FF;
        if (kg + 3 < FF) v = *(const float4*)(ap + kg);
        else {
          if (kg < FF) v.x = ap[kg];
          if (kg + 1 < FF) v.y = ap[kg + 1];
          if (kg + 2 < FF) v.z = ap[kg + 2];
        }
      }
      As[4 * lkq + 0][r] = v.x; As[4 * lkq + 1][r] = v.y;
      As[4 * lkq + 2][r] = v.z; As[4 * lkq + 3][r] = v.w;
    }
    #pragma unroll
    for (int p = 0; p < 4; ++p) {
      int kk = lkb + 8 * p;
      int kg = k0 + kk;
      float4 v = make_float4(0.f, 0.f, 0.f, 0.f);
      if (kg < FF) v = *(const float4*)&B[(size_t)kg * DD + 4 * lc4];
      *(float4*)&Bs[kk][4 * lc4] = v;
    }
    __syncthreads();
    #pragma unroll
    for (int kk = 0; kk < 32; ++kk) {
      float4 a0 = *(float4*)&As[kk][8 * ty];
      float4 a1 = *(float4*)&As[kk][8 * ty + 4];
      float4 b0 = *(float4*)&Bs[kk][4 * tx];
      float4 b1 = *(float4*)&Bs[kk][64 + 4 * tx];
      float av[8] = {a0.x, a0.y, a0.z, a0.w, a1.x, a1.y, a1.z, a1.w};
      float bv[8] = {b0.x, b0.y, b0.z, b0.w, b1.x, b1.y, b1.z, b1.w};
      #pragma unroll
      for (int i = 0; i < 8; ++i)
        #pragma unroll
        for (int j = 0; j < 8; ++j) acc[i][j] = fmaf(av[i], bv[j], acc[i][j]);
    }
    __syncthreads();
  }
  float4 bb0 = *(const float4*)&bias[4 * tx];
  float4 bb1 = *(const float4*)&bias[64 + 4 * tx];
  #pragma unroll
  for (int i = 0; i < 8; ++i) {
    int rg = row0 + 8 * ty + i;
    if (rg < NTX) {
      float4 o0 = make_float4(acc[i][0] + bb0.x, acc[i][1] + bb0.y,
                              acc[i][2] + bb0.z, acc[i][3] + bb0.w);
      float4 o1 = make_float4(acc[i][4] + bb1.x, acc[i][5] + bb1.y,
                              acc[i][6] + bb1.z, acc[i][7] + bb1.w);
      *(float4*)&C[(size_t)rg * DD + 4 * tx] = o0;
      *(float4*)&C[(size_t)rg * DD + 64 + 4 * tx] = o1;
    }
  }
}

// xw = gather(emb_t, idx_t) @ lin_w ; also a_s = xw.att_src, a_d = xw.att_dst
__global__ __launch_bounds__(256) void k_xw_att(
    const float* __restrict__ emb_t, const int* __restrict__ idx_t,
    const float* __restrict__ B, const float* __restrict__ att_s,
    const float* __restrict__ att_d, float* __restrict__ C,
    float* __restrict__ a_s, float* __restrict__ a_d) {
  __shared__ float As[32][132];
  __shared__ float Bs[32][128];
  __shared__ int sidx[128];
  int tid = threadIdx.x;
  int tx = tid & 15, ty = tid >> 4;
  int row0 = blockIdx.x * 128;
  int lkq = tid & 7, lr = tid >> 3;
  int lc4 = tid & 31, lkb = tid >> 5;
  if (tid < 128) {
    int rg = row0 + tid;
    sidx[tid] = (rg < NE) ? idx_t[rg] : 0;
  }
  __syncthreads();
  float acc[8][8];
  #pragma unroll
  for (int i = 0; i < 8; ++i)
    #pragma unroll
    for (int j = 0; j < 8; ++j) acc[i][j] = 0.f;

  for (int k0 = 0; k0 < DD; k0 += 32) {
    #pragma unroll
    for (int p = 0; p < 4; ++p) {
      int r = lr + 32 * p;
      int kg = k0 + 4 * lkq;
      float4 v = *(const float4*)(emb_t + (size_t)sidx[r] * DD + kg);
      As[4 * lkq + 0][r] = v.x; As[4 * lkq + 1][r] = v.y;
      As[4 * lkq + 2][r] = v.z; As[4 * lkq + 3][r] = v.w;
    }
    #pragma unroll
    for (int p = 0; p < 4; ++p) {
      int kk = lkb + 8 * p;
      float4 v = *(const float4*)&B[(size_t)(k0 + kk) * DD + 4 * lc4];
      *(float4*)&Bs[kk][4 * lc4] = v;
    }
    __syncthreads();
    #pragma unroll
    for (int kk = 0; kk < 32; ++kk) {
      float4 a0 = *(float4*)&As[kk][8 * ty];
      float4 a1 = *(float4*)&As[kk][8 * ty + 4];
      float4 b0 = *(float4*)&Bs[kk][4 * tx];
      float4 b1 = *(float4*)&Bs[kk][64 + 4 * tx];
      float av[8] = {a0.x, a0.y, a0.z, a0.w, a1.x, a1.y, a1.z, a1.w};
      float bv[8] = {b0.x, b0.y, b0.z, b0.w, b1.x, b1.y, b1.z, b1.w};
      #pragma unroll
      for (int i = 0; i < 8; ++i)
        #pragma unroll
        for (int j = 0; j < 8; ++j) acc[i][j] = fmaf(av[i], bv[j], acc[i][j]);
    }
    __syncthreads();
  }
  float4 sv0 = *(const float4*)&att_s[4 * tx];
  float4 sv1 = *(const float4*)&att_s[64 + 4 * tx];
  float4 dv0 = *(const float4*)&att_d[4 * tx];
  float4 dv1 = *(const float4*)&att_d[64 + 4 * tx];
  #pragma unroll
  for (int i = 0; i < 8; ++i) {
    int rg = row0 + 8 * ty + i;
    float ps = acc[i][0] * sv0.x + acc[i][1] * sv0.y + acc[i][2] * sv0.z + acc[i][3] * sv0.w
             + acc[i][4] * sv1.x + acc[i][5] * sv1.y + acc[i][6] * sv1.z + acc[i][7] * sv1.w;
    float pd = acc[i][0] * dv0.x + acc[i][1] * dv0.y + acc[i][2] * dv0.z + acc[i][3] * dv0.w
             + acc[i][4] * dv1.x + acc[i][5] * dv1.y + acc[i][6] * dv1.z + acc[i][7] * dv1.w;
    #pragma unroll
    for (int off = 8; off; off >>= 1) {
      ps += __shfl_xor(ps, off);
      pd += __shfl_xor(pd, off);
    }
    if (rg < NE) {
      *(float4*)&C[(size_t)rg * DD + 4 * tx] =
          make_float4(acc[i][0], acc[i][1], acc[i][2], acc[i][3]);
      *(float4*)&C[(size_t)rg * DD + 64 + 4 * tx] =
          make_float4(acc[i][4], acc[i][5], acc[i][6], acc[i][7]);
      if (tx == 0) { a_s[rg] = ps; a_d[rg] = pd; }
    }
  }
}

// hw = h @ w1t  (K = 128, no bias)
__global__ __launch_bounds__(256) void k_hw_gemm(
    const float* __restrict__ A, const float* __restrict__ B, float* __restrict__ C) {
  __shared__ float As[32][132];
  __shared__ float Bs[32][128];
  int tid = threadIdx.x;
  int tx = tid & 15, ty = tid >> 4;
  int row0 = blockIdx.x * 128;
  int lkq = tid & 7, lr = tid >> 3;
  int lc4 = tid & 31, lkb = tid >> 5;
  float acc[8][8];
  #pragma unroll
  for (int i = 0; i < 8; ++i)
    #pragma unroll
    for (int j = 0; j < 8; ++j) acc[i][j] = 0.f;

  for (int k0 = 0; k0 < DD; k0 += 32) {
    #pragma unroll
    for (int p = 0; p < 4; ++p) {
      int r = lr + 32 * p;
      int rg = row0 + r;
      int kg = k0 + 4 * lkq;
      float4 v = make_float4(0.f, 0.f, 0.f, 0.f);
      if (rg < NE) v = *(const float4*)(A + (size_t)rg * DD + kg);
      As[4 * lkq + 0][r] = v.x; As[4 * lkq + 1][r] = v.y;
      As[4 * lkq + 2][r] = v.z; As[4 * lkq + 3][r] = v.w;
    }
    #pragma unroll
    for (int p = 0; p < 4; ++p) {
      int kk = lkb + 8 * p;
      float4 v = *(const float4*)&B[(size_t)(k0 + kk) * DD + 4 * lc4];
      *(float4*)&Bs[kk][4 * lc4] = v;
    }
    __syncthreads();
    #pragma unroll
    for (int kk = 0; kk < 32; ++kk) {
      float4 a0 = *(float4*)&As[kk][8 * ty];
      float4 a1 = *(float4*)&As[kk][8 * ty + 4];
      float4 b0 = *(float4*)&Bs[kk][4 * tx];
      float4 b1 = *(float4*)&Bs[kk][64 + 4 * tx];
      float av[8] = {a0.x, a0.y, a0.z, a0.w, a1.x, a1.y, a1.z, a1.w};
      float bv[8] = {b0.x, b0.y, b0.z, b0.w, b1.x, b1.y, b1.z, b1.w};
      #pragma unroll
      for (int i = 0; i < 8; ++i)
        #pragma unroll
        for (int j = 0; j < 8; ++j) acc[i][j] = fmaf(av[i], bv[j], acc[i][j]);
    }
    __syncthreads();
  }
  #pragma unroll
  for (int i = 0; i < 8; ++i) {
    int rg = row0 + 8 * ty + i;
    if (rg < NE) {
      *(float4*)&C[(size_t)rg * DD + 4 * tx] =
          make_float4(acc[i][0], acc[i][1], acc[i][2], acc[i][3]);
      *(float4*)&C[(size_t)rg * DD + 64 + 4 * tx] =
          make_float4(acc[i][4], acc[i][5], acc[i][6], acc[i][7]);
    }
  }
}

// ============================================================
// CSR build kernels. t = blockIdx.y; launched with gridDim.y = TT
// (batched, pointers = full arrays) or gridDim.y = 1 (per-type,
// pointers = per-type bases) depending on workspace size.
// ============================================================
__global__ void k_hist(const int* __restrict__ dst_all, int* __restrict__ cnt_all) {
  int t = blockIdx.y;
  int i = blockIdx.x * 256 + threadIdx.x;
  if (i < EE) atomicAdd(&cnt_all[(size_t)t * NE + dst_all[(size_t)t * EE + i]], 1);
}

__global__ __launch_bounds__(256) void k_scan_a(const int* __restrict__ cnt,
                                                int* __restrict__ start,
                                                int* __restrict__ csum) {
  __shared__ int s[256];
  int t = blockIdx.y;
  int i = blockIdx.x * 256 + threadIdx.x;
  int v = (i < NE) ? cnt[(size_t)t * NE + i] : 0;
  s[threadIdx.x] = v;
  __syncthreads();
  for (int off = 1; off < 256; off <<= 1) {
    int u = (threadIdx.x >= off) ? s[threadIdx.x - off] : 0;
    __syncthreads();
    s[threadIdx.x] += u;
    __syncthreads();
  }
  if (i < NE) start[(size_t)t * NE + i] = s[threadIdx.x] - v;  // exclusive
  if (threadIdx.x == 255) csum[t * NBLK + blockIdx.x] = s[255];
}

__global__ __launch_bounds__(512) void k_scan_b(int* __restrict__ csum) {
  __shared__ int s[512];
  int t = blockIdx.y;
  int v = (threadIdx.x < NBLK) ? csum[t * NBLK + threadIdx.x] : 0;
  s[threadIdx.x] = v;
  __syncthreads();
  for (int off = 1; off < 512; off <<= 1) {
    int u = (threadIdx.x >= off) ? s[threadIdx.x - off] : 0;
    __syncthreads();
    s[threadIdx.x] += u;
    __syncthreads();
  }
  if (threadIdx.x < NBLK) csum[t * NBLK + threadIdx.x] = s[threadIdx.x] - v;  // exclusive
}

__global__ void k_scan_c(int* __restrict__ start, const int* __restrict__ csum) {
  int t = blockIdx.y;
  int i = blockIdx.x * 256 + threadIdx.x;
  if (i < NE) start[(size_t)t * NE + i] += csum[t * NBLK + blockIdx.x];
}

// eidx[p] stores the SRC node of each edge, grouped by dst; start -> end offsets
__global__ void k_fill(const int* __restrict__ src_all, const int* __restrict__ dst_all,
                       int* __restrict__ start, int* __restrict__ eidx) {
  int t = blockIdx.y;
  int i = blockIdx.x * 256 + threadIdx.x;
  if (i >= EE) return;
  int p = atomicAdd(&start[(size_t)t * NE + dst_all[(size_t)t * EE + i]], 1);
  eidx[(size_t)t * EE + p] = src_all[(size_t)t * EE + i];
}

// ============================================================
// wave-per-dst fused attention: max / exp-sum / weighted gather / +bias / LN
// ============================================================
__global__ __launch_bounds__(256) void k_dst_attn(
    const int* __restrict__ start, const int* __restrict__ eidx,
    const float* __restrict__ a_s, const float* __restrict__ a_d,
    const float* __restrict__ xw, const float* __restrict__ cbias,
    const float* __restrict__ gamma, const float* __restrict__ beta,
    float* __restrict__ h) {
  int wid = (blockIdx.x * 256 + threadIdx.x) >> 6;
  int l = threadIdx.x & 63;
  if (wid >= NE) return;
  int d = wid;
  int end = start[d];
  int beg = (d == 0) ? 0 : start[d - 1];
  float ad = a_d[d];
  float eself = leaky(a_s[d] + ad);
  const float2* xw2 = (const float2*)xw;

  float mx = eself;
  for (int base = beg; base < end; base += 64) {
    int i = base + l;
    if (i < end) mx = fmaxf(mx, leaky(a_s[eidx[i]] + ad));
  }
  #pragma unroll
  for (int off = 32; off; off >>= 1) mx = fmaxf(mx, __shfl_xor(mx, off));

  float wself = expf(eself - mx);
  float denom = wself;
  float2 acc;
  float2 xs = xw2[(size_t)d * 64 + l];
  acc.x = wself * xs.x;
  acc.y = wself * xs.y;
  for (int base = beg; base < end; base += 64) {
    int len = end - base; if (len > 64) len = 64;
    int i = base + l;
    int sv = (i < end) ? eidx[i] : 0;
    float av = (i < end) ? a_s[sv] : 0.f;
    for (int j = 0; j < len; ++j) {
      int s = __shfl(sv, j);
      float a = __shfl(av, j);
      float w = expf(leaky(a + ad) - mx);
      denom += w;
      float2 v = xw2[(size_t)s * 64 + l];
      acc.x = fmaf(w, v.x, acc.x);
      acc.y = fmaf(w, v.y, acc.y);
    }
  }
  float inv = 1.f / (denom + 1e-16f);
  float2 cb = ((const float2*)cbias)[l];
  float v0 = acc.x * inv + cb.x;
  float v1 = acc.y * inv + cb.y;

  float s = v0 + v1;
  #pragma unroll
  for (int off = 32; off; off >>= 1) s += __shfl_xor(s, off);
  float mean = s * (1.f / 128.f);
  float d0 = v0 - mean, d1 = v1 - mean;
  float q = d0 * d0 + d1 * d1;
  #pragma unroll
  for (int off = 32; off; off >>= 1) q += __shfl_xor(q, off);
  float r = rsqrtf(q * (1.f / 128.f) + 1e-5f);
  float2 g = ((const float2*)gamma)[l];
  float2 b = ((const float2*)beta)[l];
  float2 o = make_float2(d0 * r * g.x + b.x, d1 * r * g.y + b.y);
  ((float2*)h)[(size_t)d * 64 + l] = o;
}

// wave-per-dst: acc1[d] += sum over edges of hw[src]
__global__ __launch_bounds__(256) void k_dst_sum_acc(
    const int* __restrict__ start, const int* __restrict__ eidx,
    const float* __restrict__ hw, float* __restrict__ acc1) {
  int wid = (blockIdx.x * 256 + threadIdx.x) >> 6;
  int l = threadIdx.x & 63;
  if (wid >= NE) return;
  int d = wid;
  int end = start[d];
  int beg = (d == 0) ? 0 : start[d - 1];
  if (beg == end) return;
  const float2* hw2 = (const float2*)hw;
  float2 acc = make_float2(0.f, 0.f);
  for (int base = beg; base < end; base += 64) {
    int len = end - base; if (len > 64) len = 64;
    int i = base + l;
    int sv = (i < end) ? eidx[i] : 0;
    for (int j = 0; j < len; ++j) {
      int s = __shfl(sv, j);
      float2 v = hw2[(size_t)s * 64 + l];
      acc.x += v.x;
      acc.y += v.y;
    }
  }
  float2* p = (float2*)acc1 + (size_t)d * 64 + l;
  float2 old = *p;
  *p = make_float2(old.x + acc.x, old.y + acc.y);
}

// fused classifier tail
__global__ __launch_bounds__(128) void k_tail(
    const float* __restrict__ acc1, const float* __restrict__ w2,
    const float* __restrict__ b2, const float* __restrict__ w3,
    const float* __restrict__ b3, float* __restrict__ out) {
  __shared__ float h1[DD];
  __shared__ float h2s[64];
  int n = blockIdx.x, tid = threadIdx.x;
  float v = acc1[(size_t)n * DD + tid];
  h1[tid] = v > 0.f ? v : 0.f;
  __syncthreads();
  if (tid < 64) {
    float acc = b2[tid];
    for (int k = 0; k < DD; ++k) acc = fmaf(h1[k], w2[k * 64 + tid], acc);
    h2s[tid] = acc > 0.f ? acc : 0.f;
  }
  __syncthreads();
  if (tid < 64) {
    float p = h2s[tid] * w3[tid];
    #pragma unroll
    for (int off = 32; off; off >>= 1) p += __shfl_down(p, off);
    if (tid == 0) out[n] = p + b3[0];
  }
}

// ---------- launch ----------

extern "C" void kernel_launch(void* const* d_in, const int* in_sizes, int n_in,
                              void* d_out, int out_size, void* d_ws, size_t ws_size,
                              hipStream_t stream) {
  const float* tx_x     = (const float*)d_in[0];
  const float* emb      = (const float*)d_in[1];
  const float* lin_w    = (const float*)d_in[2];
  const float* att_src  = (const float*)d_in[3];
  const float* att_dst  = (const float*)d_in[4];
  const float* conv_bias= (const float*)d_in[5];
  const float* ln_gamma = (const float*)d_in[6];
  const float* ln_beta  = (const float*)d_in[7];
  const float* w1       = (const float*)d_in[8];
  const float* b1       = (const float*)d_in[9];
  const float* w2       = (const float*)d_in[10];
  const float* b2       = (const float*)d_in[11];
  const float* w3       = (const float*)d_in[12];
  const float* b3       = (const float*)d_in[13];
  const int* entity_idx = (const int*)d_in[14];
  const int* edge_src   = (const int*)d_in[15];
  const int* edge_dst   = (const int*)d_in[16];
  float* out = (float*)d_out;

  float* ws   = (float*)d_ws;
  float* acc1 = ws;                          // NTX*DD floats
  float* xw   = acc1 + (size_t)NTX * DD;     // NE*DD (aliased as hw later)
  float* h    = xw + (size_t)NE * DD;        // NE*DD (cnt/csum alias during CSR build)
  float* a_s  = h + (size_t)NE * DD;         // NE
  float* a_d  = a_s + NE;                    // NE
  int* start_base = (int*)(a_d + NE);        // NE (per-type) or TT*NE (batched)
  float* hw   = xw;

  // Decide layout from the ACTUAL workspace size (known at capture time).
  size_t base_floats = (size_t)NTX * DD + 2 * (size_t)NE * DD + 2 * (size_t)NE;
  size_t need_batched = base_floats * sizeof(float)
                      + ((size_t)TT * NE + (size_t)TT * EE) * sizeof(int);
  bool batched = ws_size >= need_batched;

  const int GB = (NE + 127) / 128;           // 782 GEMM blocks (NE == NTX)
  const int EB = (EE + 255) / 256;

  k_init_gemm<<<(NTX + 127) / 128, 256, 0, stream>>>(tx_x, w1, b1, acc1);

  if (batched) {
    int* start_all = start_base;                       // TT*NE
    int* eidx_all  = start_all + (size_t)TT * NE;      // TT*EE
    int* cnt_all   = (int*)h;                          // alias: h dead during CSR build
    int* csum      = cnt_all + (size_t)TT * NE;        // TT*NBLK, still inside h

    hipMemsetAsync(cnt_all, 0, (size_t)TT * NE * sizeof(int), stream);
    k_hist<<<dim3(EB, TT), 256, 0, stream>>>(edge_dst, cnt_all);
    k_scan_a<<<dim3(NBLK, TT), 256, 0, stream>>>(cnt_all, start_all, csum);
    k_scan_b<<<dim3(1, TT), 512, 0, stream>>>(csum);
    k_scan_c<<<dim3(NBLK, TT), 256, 0, stream>>>(start_all, csum);
    k_fill<<<dim3(EB, TT), 256, 0, stream>>>(edge_src, edge_dst, start_all, eidx_all);

    for (int t = 0; t < TT; ++t) {
      const float* emb_t = emb + (size_t)t * NE * DD;
      const int* idx_t   = entity_idx + (size_t)t * NE;
      const float* gamma = ln_gamma + t * DD;
      const float* beta  = ln_beta + t * DD;
      const float* w1t   = w1 + (size_t)(FF + t * DD) * DD;
      const int* start_t = start_all + (size_t)t * NE;
      const int* eidx_t  = eidx_all + (size_t)t * EE;

      k_xw_att<<<GB, 256, 0, stream>>>(emb_t, idx_t, lin_w, att_src, att_dst,
                                       xw, a_s, a_d);
      k_dst_attn<<<(NE + 3) / 4, 256, 0, stream>>>(start_t, eidx_t, a_s, a_d, xw,
                                                   conv_bias, gamma, beta, h);
      k_hw_gemm<<<GB, 256, 0, stream>>>(h, w1t, hw);
      k_dst_sum_acc<<<(NE + 3) / 4, 256, 0, stream>>>(start_t, eidx_t, hw, acc1);
    }
  } else {
    // Per-type CSR build (proven round-0 footprint: NE + EE ints past a_d)
    int* start = start_base;                 // NE
    int* eidx  = start + NE;                 // EE
    int* cnt   = (int*)h;                    // alias: h dead during CSR build
    int* csum  = cnt + (size_t)NE;           // NBLK ints, inside h

    for (int t = 0; t < TT; ++t) {
      const float* emb_t = emb + (size_t)t * NE * DD;
      const int* idx_t   = entity_idx + (size_t)t * NE;
      const int* src     = edge_src + (size_t)t * EE;
      const int* dst     = edge_dst + (size_t)t * EE;
      const float* gamma = ln_gamma + t * DD;
      const float* beta  = ln_beta + t * DD;
      const float* w1t   = w1 + (size_t)(FF + t * DD) * DD;

      k_xw_att<<<GB, 256, 0, stream>>>(emb_t, idx_t, lin_w, att_src, att_dst,
                                       xw, a_s, a_d);
      hipMemsetAsync(cnt, 0, NE * sizeof(int), stream);
      k_hist<<<dim3(EB, 1), 256, 0, stream>>>(dst, cnt);
      k_scan_a<<<dim3(NBLK, 1), 256, 0, stream>>>(cnt, start, csum);
      k_scan_b<<<dim3(1, 1), 512, 0, stream>>>(csum);
      k_scan_c<<<dim3(NBLK, 1), 256, 0, stream>>>(start, csum);
      k_fill<<<dim3(EB, 1), 256, 0, stream>>>(src, dst, start, eidx);
      k_dst_attn<<<(NE + 3) / 4, 256, 0, stream>>>(start, eidx, a_s, a_d, xw,
                                                   conv_bias, gamma, beta, h);
      k_hw_gemm<<<GB, 256, 0, stream>>>(h, w1t, hw);
      k_dst_sum_acc<<<(NE + 3) / 4, 256, 0, stream>>>(start, eidx, hw, acc1);
    }
  }

  k_tail<<<NTX, DD, 0, stream>>>(acc1, w2, b2, w3, b3, out);
}